// Round 3
// baseline (89.537 us; speedup 1.0000x reference)
//
#include <hip/hip_runtime.h>

#define N 384
#define D 128

// 100/ln(2) = 100*log2(e): sigmoid(x*100) with exp2
// exp(-(sac-sab)*100) = exp2((sab-sac)*KLOG2E)
__device__ const float KLOG2E = 144.26950408889634f;  // 100 * log2(e)
__device__ const float ECLAMP = 72.13475204444817f;   // 50 * log2(e)  (the ±50 clip)

__global__ __launch_bounds__(N) void smoothap_main(const float* __restrict__ preds,
                                                   const int* __restrict__ labels,
                                                   float* __restrict__ per_a) {
    __shared__ float4 s_pa[D / 4];   // preds[a, :]
    __shared__ float2 s_sp[N];       // (sim[a,c], posmask[a,c])
    __shared__ int    s_lab[N];
    __shared__ float  s_red[12];

    const int a = blockIdx.x;
    const int t = threadIdx.x;       // t == b

    if (t < D / 4) s_pa[t] = ((const float4*)(preds + (size_t)a * D))[t];
    s_lab[t] = labels[t];
    __syncthreads();

    // sim[a, t] = dot(preds[a], preds[t])
    const float4* pt = (const float4*)(preds + (size_t)t * D);
    float acc = 0.f;
#pragma unroll
    for (int k = 0; k < D / 4; ++k) {
        float4 v = pt[k];
        float4 w = s_pa[k];
        acc = fmaf(v.x, w.x, acc);
        acc = fmaf(v.y, w.y, acc);
        acc = fmaf(v.z, w.z, acc);
        acc = fmaf(v.w, w.w, acc);
    }
    const int la = s_lab[a];
    const float posf = (s_lab[t] == la && t != a) ? 1.f : 0.f;  // I_pos[a, t]
    s_sp[t] = make_float2(acc, posf);
    __syncthreads();

    const float simab = acc;
    const float mab = simab * KLOG2E;

    float all_sum = 0.f;
    float pos_sum = 0.f;
    const float4* sp4 = (const float4*)s_sp;  // (sim[2j], pos[2j], sim[2j+1], pos[2j+1])
#pragma unroll 4
    for (int j = 0; j < N / 2; ++j) {
        float4 q = sp4[j];
        // sg = sigmoid(clip((sim[a,c]-sim[a,b])/0.01, -50, 50)) = 1/(1+exp2(e)), e=(sab-sac)*K
        float e0 = fmaf(q.x, -KLOG2E, mab);
        e0 = fminf(fmaxf(e0, -ECLAMP), ECLAMP);
        float sg0 = __builtin_amdgcn_rcpf(1.f + __builtin_amdgcn_exp2f(e0));
        float e1 = fmaf(q.z, -KLOG2E, mab);
        e1 = fminf(fmaxf(e1, -ECLAMP), ECLAMP);
        float sg1 = __builtin_amdgcn_rcpf(1.f + __builtin_amdgcn_exp2f(e1));
        all_sum += sg0 + sg1;
        pos_sum = fmaf(sg0, q.y, pos_sum);
        pos_sum = fmaf(sg1, q.w, pos_sum);
    }
    // remove the b==c term (reference zeroes it); it is exactly sigmoid(0)=0.5
    all_sum -= 0.5f;
    pos_sum -= 0.5f * posf;

    // sim_pos_rk/sim_all_rk for this (a,b):
    // num = 1 + I_pos[a,b] + I_pos[a,b]*pos_sum ; den = 1 + all_sum
    const float ratio = fmaf(posf, 1.f + pos_sum, 1.f) / (1.f + all_sum);

    // block reduce: sum(ratio) over b, and sum(posf) over b (= n_pos - 1)
    const int lane = t & 63;
    const int wid = t >> 6;
    float r = ratio;
    float np = posf;
#pragma unroll
    for (int off = 32; off; off >>= 1) {
        r += __shfl_down(r, off);
        np += __shfl_down(np, off);
    }
    if (lane == 0) {
        s_red[wid] = r;
        s_red[6 + wid] = np;
    }
    __syncthreads();
    if (t == 0) {
        float rs = 0.f, ns = 0.f;
#pragma unroll
        for (int w = 0; w < 6; ++w) {
            rs += s_red[w];
            ns += s_red[6 + w];
        }
        const float n_pos = ns + 1.f;
        per_a[a] = (ns > 0.5f) ? (rs / n_pos) : 0.f;
    }
}

__global__ __launch_bounds__(N) void smoothap_final(const float* __restrict__ per_a,
                                                    float* __restrict__ out) {
    __shared__ float s_red[6];
    const int t = threadIdx.x;
    float v = per_a[t];
    const int lane = t & 63;
    const int wid = t >> 6;
#pragma unroll
    for (int off = 32; off; off >>= 1) v += __shfl_down(v, off);
    if (lane == 0) s_red[wid] = v;
    __syncthreads();
    if (t == 0) {
        float s = 0.f;
#pragma unroll
        for (int w = 0; w < 6; ++w) s += s_red[w];
        out[0] = 1.f - s / (float)N;
    }
}

extern "C" void kernel_launch(void* const* d_in, const int* in_sizes, int n_in,
                              void* d_out, int out_size, void* d_ws, size_t ws_size,
                              hipStream_t stream) {
    const float* preds = (const float*)d_in[0];
    const int* labels = (const int*)d_in[1];
    float* out = (float*)d_out;
    float* per_a = (float*)d_ws;  // N floats of scratch

    smoothap_main<<<N, N, 0, stream>>>(preds, labels, per_a);
    smoothap_final<<<1, N, 0, stream>>>(per_a, out);
}

// Round 4
// 82.744 us; speedup vs baseline: 1.0821x; 1.0821x over previous
//
#include <hip/hip_runtime.h>

#define N 384
#define NT 768
#define HALF_ITERS 96  // each half covers 192 c's = 96 float4 reads

// sigmoid((sac-sab)/0.01) = 1/(1+exp2((sab-sac)*100*log2(e)))
// The reference's clip(+-50) is a numerical no-op in fp32: beyond |x|=17 the
// sigmoid saturates to 0.0f/1.0f either way (exp2 over/underflow -> rcp gives
// exactly 0 or 1; clipped path differs by <2e-22, threshold is 1.1e-2).
__device__ const float KLOG2E = 144.26950408889634f;  // 100 * log2(e)

__global__ __launch_bounds__(NT) void smoothap_fused(const float* __restrict__ preds,
                                                     const int* __restrict__ labels,
                                                     float* __restrict__ out) {
    __shared__ __align__(16) float4 s_pa[32];    // preds[a,:]
    __shared__ __align__(16) float2 s_sp[N];     // (sim[a,c], I_pos[a,c])
    __shared__ __align__(16) float2 s_part[N];   // half-1 partial sums
    __shared__ int   s_lab[N];
    __shared__ float s_red[24];                  // 12 waves x {ratio, posf}

    const int a = blockIdx.x;
    const int t = threadIdx.x;
    const int half = (t >= N) ? 1 : 0;
    const int b = t - half * N;                  // this thread's b index

    if (t < N) s_lab[t] = labels[t];
    if (t < 32) s_pa[t] = ((const float4*)(preds + (size_t)a * 128))[t];
    __syncthreads();

    // sim[a,t] = dot(preds[a], preds[t]) — computed by the low half
    if (t < N) {
        const float4* pt = (const float4*)(preds + (size_t)t * 128);
        float acc = 0.f;
#pragma unroll
        for (int k = 0; k < 32; ++k) {
            float4 v = pt[k];
            float4 w = s_pa[k];
            acc = fmaf(v.x, w.x, acc);
            acc = fmaf(v.y, w.y, acc);
            acc = fmaf(v.z, w.z, acc);
            acc = fmaf(v.w, w.w, acc);
        }
        const float posf = (s_lab[t] == s_lab[a] && t != a) ? 1.f : 0.f;
        s_sp[t] = make_float2(acc, posf);
    }
    __syncthreads();

    const float2 me = s_sp[b];
    const float mab = me.x * KLOG2E;
    const float posf = me.y;

    // each half sums its 192 c's
    float all_sum = 0.f, pos_sum = 0.f;
    const float4* sp4 = (const float4*)s_sp;  // (sim[2j], pos[2j], sim[2j+1], pos[2j+1])
    const int j0 = half * HALF_ITERS;
#pragma unroll 4
    for (int j = j0; j < j0 + HALF_ITERS; ++j) {
        float4 q = sp4[j];
        float e0 = fmaf(q.x, -KLOG2E, mab);
        float sg0 = __builtin_amdgcn_rcpf(1.f + __builtin_amdgcn_exp2f(e0));
        float e1 = fmaf(q.z, -KLOG2E, mab);
        float sg1 = __builtin_amdgcn_rcpf(1.f + __builtin_amdgcn_exp2f(e1));
        all_sum += sg0 + sg1;
        pos_sum = fmaf(sg0, q.y, pos_sum);
        pos_sum = fmaf(sg1, q.w, pos_sum);
    }
    if (half) s_part[b] = make_float2(all_sum, pos_sum);
    __syncthreads();

    // combine halves, remove the b==c diagonal term (sigmoid(0)=0.5 exactly)
    float r = 0.f, np = 0.f;
    if (t < N) {
        const float2 o = s_part[b];
        const float all = all_sum + o.x - 0.5f;
        const float pos = pos_sum + o.y - 0.5f * posf;
        r = fmaf(posf, 1.f + pos, 1.f) / (1.f + all);
        np = posf;
    }

    // block reduce over all 12 waves (upper-half threads contribute 0)
    const int lane = t & 63;
    const int wid = t >> 6;
#pragma unroll
    for (int off = 32; off; off >>= 1) {
        r += __shfl_down(r, off);
        np += __shfl_down(np, off);
    }
    if (lane == 0) {
        s_red[wid] = r;
        s_red[12 + wid] = np;
    }
    __syncthreads();
    if (t == 0) {
        float rs = 0.f, ns = 0.f;
#pragma unroll
        for (int w = 0; w < 12; ++w) {
            rs += s_red[w];
            ns += s_red[12 + w];
        }
        const float per_i = (ns > 0.5f) ? rs / (ns + 1.f) : 0.f;
        // out = 1 - sum_a(per_i)/N : block 0 contributes the +1
        const float contrib = fmaf(per_i, -1.f / (float)N, (a == 0) ? 1.f : 0.f);
        atomicAdd(out, contrib);
    }
}

extern "C" void kernel_launch(void* const* d_in, const int* in_sizes, int n_in,
                              void* d_out, int out_size, void* d_ws, size_t ws_size,
                              hipStream_t stream) {
    const float* preds = (const float*)d_in[0];
    const int* labels = (const int*)d_in[1];
    float* out = (float*)d_out;

    hipMemsetAsync(out, 0, sizeof(float), stream);
    smoothap_fused<<<N, NT, 0, stream>>>(preds, labels, out);
}